// Round 11
// baseline (239.264 us; speedup 1.0000x reference)
//
#include <hip/hip_runtime.h>
#include <hip/hip_bf16.h>
#include <stdint.h>

#define B_ 4
#define S_ 2048
#define H_ 1024
#define NH_ 16
#define DH_ 64
#define M_ (B_*S_)   // 8192

typedef __bf16 bf16x8 __attribute__((ext_vector_type(8)));
typedef float f32x4 __attribute__((ext_vector_type(4)));

static_assert(sizeof(__bf16) == 2, "bf16 size");

__device__ __forceinline__ uint32_t pack_bf16(float lo, float hi)
{
    union { __bf16 h[2]; uint32_t u; } t;
    t.h[0] = (__bf16)lo; t.h[1] = (__bf16)hi;
    return t.u;
}

__device__ __forceinline__ float fast_exp2(float x)
{
#if __has_builtin(__builtin_amdgcn_exp2f)
    return __builtin_amdgcn_exp2f(x);
#else
    return exp2f(x);
#endif
}

// async global->LDS, 16B per lane. LDS dest = wave-uniform base + lane*16.
__device__ __forceinline__ void gll16(void* lds, const void* g)
{
    __builtin_amdgcn_global_load_lds(
        (const __attribute__((address_space(1))) unsigned int*)g,
        (__attribute__((address_space(3))) unsigned int*)lds,
        16, 0, 0);
}

// ---------------------------------------------------------------- cast ----
__global__ __launch_bounds__(256)
void cast_f32_bf16(const float* __restrict__ src, __bf16* __restrict__ dst, int n)
{
    int i = (blockIdx.x * 256 + threadIdx.x) * 8;
    if (i < n) {
        float4 a = *(const float4*)(src + i);
        float4 b = *(const float4*)(src + i + 4);
        bf16x8 o;
        o[0] = (__bf16)a.x; o[1] = (__bf16)a.y; o[2] = (__bf16)a.z; o[3] = (__bf16)a.w;
        o[4] = (__bf16)b.x; o[5] = (__bf16)b.y; o[6] = (__bf16)b.z; o[7] = (__bf16)b.w;
        *(bf16x8*)(dst + i) = o;
    }
}

// ------------------------------------------------------- mask prescale ----
__global__ __launch_bounds__(256)
void prescale_mask(const float* __restrict__ m, float* __restrict__ o)
{
    int i = blockIdx.x * 256 + threadIdx.x;
    o[i] = m[i] * 1.44269504089f;
}

// ---------------------------------------------------------------- GEMM ----
// C[M,N] = A[M,K] @ Bw[N,K]^T + bias. bf16 in, fp32 acc.
// EPI 1: fp32 out + resid (Wo proj). EPI 3: fused QKV -> q, k, V^T.
template<int EPI>
__global__ __launch_bounds__(256)
void gemm_bt(const __bf16* __restrict__ A, const __bf16* __restrict__ Bw,
             const float* __restrict__ bias, const float* __restrict__ resid,
             float* __restrict__ outf, __bf16* __restrict__ outq,
             __bf16* __restrict__ outk, __bf16* __restrict__ outvt)
{
    __shared__ __align__(16) char As[128 * 128];
    __shared__ __align__(16) char Bs[128 * 128];

    const int tid  = threadIdx.x;
    const int lane = tid & 63, wv = tid >> 6;
    const int wr = wv >> 1, wc = wv & 1;           // 2x2 wave grid, 64x64 each
    const int m0 = blockIdx.y * 128, n0 = blockIdx.x * 128;
    const int rl = lane & 15, rg = lane >> 4;
    const int r8 = lane >> 3, sl = lane & 7;       // staging: row-in-group, slot

    f32x4 acc[4][4] = {};

    for (int k0 = 0; k0 < H_; k0 += 64) {
#pragma unroll
        for (int p = 0; p < 4; ++p) {
            const int row = p * 32 + wv * 8 + r8;
            gll16(As + (size_t)(p * 32 + wv * 8) * 128,
                  A  + (size_t)(m0 + row) * H_ + k0 + 8 * (sl ^ (row & 7)));
            gll16(Bs + (size_t)(p * 32 + wv * 8) * 128,
                  Bw + (size_t)(n0 + row) * H_ + k0 + 8 * (sl ^ (row & 7)));
        }
        __syncthreads();
#pragma unroll
        for (int ks = 0; ks < 2; ++ks) {
            const int kb = ks * 64 + rg * 16;      // byte offset in LDS row
            bf16x8 af[4], bfr[4];
#pragma unroll
            for (int m = 0; m < 4; ++m) {
                const int row = wr * 64 + m * 16 + rl;
                af[m] = *(const bf16x8*)(As + row * 128 + (kb ^ ((rl & 7) << 4)));
            }
#pragma unroll
            for (int n = 0; n < 4; ++n) {
                const int row = wc * 64 + n * 16 + rl;
                bfr[n] = *(const bf16x8*)(Bs + row * 128 + (kb ^ ((rl & 7) << 4)));
            }
#pragma unroll
            for (int m = 0; m < 4; ++m)
#pragma unroll
                for (int n = 0; n < 4; ++n)
                    acc[m][n] = __builtin_amdgcn_mfma_f32_16x16x32_bf16(af[m], bfr[n], acc[m][n], 0, 0, 0);
        }
        __syncthreads();
    }

    // epilogue: C/D layout col = lane&15, row = (lane>>4)*4 + reg   [m89]
#pragma unroll
    for (int m = 0; m < 4; ++m) {
#pragma unroll
        for (int n = 0; n < 4; ++n) {
            const int col = n0 + wc * 64 + n * 16 + rl;
            const float bv = bias[col];
            const int row0 = m0 + wr * 64 + m * 16 + rg * 4;
            if (EPI == 1) {
#pragma unroll
                for (int r = 0; r < 4; ++r) {
                    const size_t idx = (size_t)(row0 + r) * H_ + col;
                    outf[idx] = acc[m][n][r] + bv + resid[idx];
                }
            } else {
                const int seg = n0 >> 10;          // block-uniform
                const int cs = col & 1023;
                if (seg < 2) {
                    __bf16* o = (seg == 0) ? outq : outk;
#pragma unroll
                    for (int r = 0; r < 4; ++r)
                        o[(size_t)(row0 + r) * H_ + cs] = (__bf16)(acc[m][n][r] + bv);
                } else {
                    const int bb = row0 >> 11, s0v = row0 & (S_ - 1);
                    const int hh = cs >> 6, dd = cs & (DH_ - 1);
                    __bf16* vtp = outvt + ((size_t)(bb * NH_ + hh) * DH_ + dd) * S_ + s0v;
                    *(uint32_t*)(vtp)     = pack_bf16(acc[m][n][0] + bv, acc[m][n][1] + bv);
                    *(uint32_t*)(vtp + 2) = pack_bf16(acc[m][n][2] + bv, acc[m][n][3] + bv);
                }
            }
        }
    }
}

// ------------------------------------------------------------ attention ----
// Swapped QK^T + permuted-K LDS -> lane-local x32 B-fragments for PV & lsum.
// 16 q-rows/WAVE (8192 waves total = 8/SIMD), 8-wave blocks, KVBLK=64,
// 32 KB dbuf LDS -> 4 blocks/CU (2048 thr = CU max). Fixed-m softmax.
// Counted-vmcnt dbuf (2 gll16/thread/tile), XCD-swizzled 1024-block grid.
__global__ __launch_bounds__(512, 8)
void attn_fwd(const __bf16* __restrict__ q, const __bf16* __restrict__ k,
              const __bf16* __restrict__ vt, const float* __restrict__ msk2,
              __bf16* __restrict__ ctx)
{
    __shared__ __align__(16) char KVs[2 * 16384];   // 32 KB: buf x (K 8K | V 8K)

    // XCD swizzle: phys%8 = XCD; 128 consecutive orig per XCD (8 heads).
    const int phys = blockIdx.x;
    const int orig = (phys & 7) * 128 + (phys >> 3);
    const int qt0 = (orig & 15) * 128;         // 16 q-tiles of 128 rows
    const int hg = orig >> 4;                  // global head 0..63
    const int h = hg & (NH_ - 1), b = hg >> 4;

    const int tid = threadIdx.x, lane = tid & 63, wv = tid >> 6;   // wv 0..7
    const int rl = lane & 15, rg = lane >> 4;
    const int swz = (rl & 7) << 4;
    const float SC = 0.125f * 1.44269504089f;      // 1/sqrt(64) * log2(e)
    const float* mbase2 = msk2 + (size_t)b * S_ + rg * 8;

    // Q as B-fragment (col = q = rl, k-elems dh = rg*8+j); wave owns 16 rows
    bf16x8 qf[2];
#pragma unroll
    for (int ks = 0; ks < 2; ++ks)
        qf[ks] = *(const bf16x8*)(q + (size_t)(b * S_ + qt0 + wv * 16 + rl) * H_
                                    + h * DH_ + ks * 32 + rg * 8);

    f32x4 cacc[4] = {};
    f32x4 lacc = {};
    bf16x8 ones8;
#pragma unroll
    for (int i = 0; i < 8; ++i) ones8[i] = (__bf16)1.0f;

    // staging geometry: K tile 64 rows x 128 B, V tile 64 rows x 128 B;
    // 512 threads stage each in ONE gll16 round (8 rows/wave, 8 slots).
    const int sR = lane >> 3, sS = lane & 7;
    const __bf16* kbase = k  + (size_t)b * S_ * H_ + h * DH_;
    const __bf16* vbase = vt + (size_t)(b * NH_ + h) * DH_ * S_;

    // K-row permutation: LDS row r holds physical key perm(r) of the tile
    auto permk = [](int r) {
        return 32 * (r >> 5) + 8 * ((r >> 2) & 3) + 4 * ((r >> 4) & 1) + (r & 3);
    };

    auto stage = [&](int buf, int kt0) {
        char* Ks = KVs + buf * 16384;
        char* Vs = Ks + 8192;
        const int krow = wv * 8 + sR;
        gll16(Ks + (size_t)(wv * 8) * 128,
              kbase + (size_t)(kt0 + permk(krow)) * H_ + 8 * (sS ^ (krow & 7)));
        const int vrow = wv * 8 + sR;
        gll16(Vs + (size_t)(wv * 8) * 128,
              vbase + (size_t)vrow * S_ + kt0 + 8 * (sS ^ (vrow & 7)));
    };

    stage(0, 0);                                    // prologue: tile 0 in flight

    const int NT = S_ / 64;
    for (int t = 0; t < NT; ++t) {
        const int cur = t & 1;
        const char* Ks = KVs + cur * 16384;
        const char* Vs = Ks + 8192;
        const int kt0 = t * 64;

        if (t + 1 < NT) {
            stage(cur ^ 1, kt0 + 64);               // issue next tile (2 loads)
            asm volatile("s_waitcnt vmcnt(2)" ::: "memory");  // tile t landed
        } else {
            asm volatile("s_waitcnt vmcnt(0)" ::: "memory");
        }
        __builtin_amdgcn_s_barrier();               // tile t visible to all
        __builtin_amdgcn_sched_barrier(0);

        // ---- per-32-key pipeline: QK(2 chunks) -> exp2/pack -> lsum+PV @x32
#pragma unroll
        for (int t4 = 0; t4 < 2; ++t4) {
            union { uint32_t u[4]; bf16x8 v; } pb;
#pragma unroll
            for (int half = 0; half < 2; ++half) {
                const int c = 2 * t4 + half;
                bf16x8 kf0 = *(const bf16x8*)(Ks + (c * 16 + rl) * 128 + ((rg * 16) ^ swz));
                bf16x8 kf1 = *(const bf16x8*)(Ks + (c * 16 + rl) * 128 + ((64 + rg * 16) ^ swz));
                f32x4 s0 = {0, 0, 0, 0};
                s0 = __builtin_amdgcn_mfma_f32_16x16x32_bf16(kf0, qf[0], s0, 0, 0, 0);
                s0 = __builtin_amdgcn_mfma_f32_16x16x32_bf16(kf1, qf[1], s0, 0, 0, 0);

                // physical keys 32*t4 + 8*rg + 4*half + {0..3}
                f32x4 m4 = *(const f32x4*)(mbase2 + kt0 + 32 * t4 + 4 * half);
                float p0 = fast_exp2(fmaf(s0[0], SC, m4[0]));
                float p1 = fast_exp2(fmaf(s0[1], SC, m4[1]));
                float p2 = fast_exp2(fmaf(s0[2], SC, m4[2]));
                float p3 = fast_exp2(fmaf(s0[3], SC, m4[3]));
                pb.u[half * 2]     = pack_bf16(p0, p1);
                pb.u[half * 2 + 1] = pack_bf16(p2, p3);
            }
            lacc = __builtin_amdgcn_mfma_f32_16x16x32_bf16(ones8, pb.v, lacc, 0, 0, 0);
#pragma unroll
            for (int n = 0; n < 4; ++n) {
                bf16x8 af = *(const bf16x8*)(Vs + (n * 16 + rl) * 128 + ((t4 * 64 + rg * 16) ^ swz));
                cacc[n] = __builtin_amdgcn_mfma_f32_16x16x32_bf16(af, pb.v, cacc[n], 0, 0, 0);
            }
        }

        // all reads of buf `cur` retired before next iter restages into it
        asm volatile("s_waitcnt lgkmcnt(0)" ::: "memory");
        __builtin_amdgcn_s_barrier();
    }

    // ---- normalize + write ctx [B,S,H] bf16 (O^T: lane has q=rl, d=rg*4+r)
    {
        const float inv = 1.f / lacc[0];           // ones-MFMA: col-sum for q=rl
        const int row = qt0 + wv * 16 + rl;
        __bf16* cb = ctx + (size_t)(b * S_ + row) * H_ + h * DH_;
#pragma unroll
        for (int n = 0; n < 4; ++n) {
            uint32_t u0 = pack_bf16(cacc[n][0] * inv, cacc[n][1] * inv);
            uint32_t u1 = pack_bf16(cacc[n][2] * inv, cacc[n][3] * inv);
            *(uint32_t*)(cb + n * 16 + rg * 4)     = u0;
            *(uint32_t*)(cb + n * 16 + rg * 4 + 2) = u1;
        }
    }
}

// ------------------------------------------------------------ layernorm ----
__global__ __launch_bounds__(256)
void ln_kernel(const float* __restrict__ x, const float* __restrict__ gamma,
               const float* __restrict__ beta, float* __restrict__ out)
{
    const int row = blockIdx.x;
    const int t = threadIdx.x;
    const float* xr = x + (size_t)row * H_;
    float4 v = *(const float4*)(xr + t * 4);
    float s  = v.x + v.y + v.z + v.w;
    float ss = v.x * v.x + v.y * v.y + v.z * v.z + v.w * v.w;
#pragma unroll
    for (int off = 1; off < 64; off <<= 1) {
        s  += __shfl_xor(s, off, 64);
        ss += __shfl_xor(ss, off, 64);
    }
    __shared__ float sb[8];
    const int wv = t >> 6, lane = t & 63;
    if (lane == 0) { sb[wv] = s; sb[4 + wv] = ss; }
    __syncthreads();
    s  = sb[0] + sb[1] + sb[2] + sb[3];
    ss = sb[4] + sb[5] + sb[6] + sb[7];
    const float mu = s * (1.f / H_);
    const float var = ss * (1.f / H_) - mu * mu;
    const float rstd = rsqrtf(var + 1e-12f);
    float4 g = *(const float4*)(gamma + t * 4);
    float4 bt = *(const float4*)(beta + t * 4);
    float4 o;
    o.x = (v.x - mu) * rstd * g.x + bt.x;
    o.y = (v.y - mu) * rstd * g.y + bt.y;
    o.z = (v.z - mu) * rstd * g.z + bt.z;
    o.w = (v.w - mu) * rstd * g.w + bt.w;
    *(float4*)(out + (size_t)row * H_ + t * 4) = o;
}

// -------------------------------------------------------------- launch ----
extern "C" void kernel_launch(void* const* d_in, const int* in_sizes, int n_in,
                              void* d_out, int out_size, void* d_ws, size_t ws_size,
                              hipStream_t stream)
{
    const float* hs    = (const float*)d_in[0];
    const float* mask  = (const float*)d_in[1];
    const float* Wq    = (const float*)d_in[2];
    const float* bq    = (const float*)d_in[3];
    const float* Wk    = (const float*)d_in[4];
    const float* bk    = (const float*)d_in[5];
    const float* Wv    = (const float*)d_in[6];
    const float* bv    = (const float*)d_in[7];
    const float* Wo    = (const float*)d_in[8];
    const float* bo    = (const float*)d_in[9];
    const float* gamma = (const float*)d_in[10];
    const float* beta  = (const float*)d_in[11];

    char* ws = (char*)d_ws;
    const size_t MB = 1ull << 20;
    __bf16* x_bf   = (__bf16*)(ws);             // 16 MB (dead after QKV GEMM)
    __bf16* wqkv   = (__bf16*)(ws + 16 * MB);   // 6 MB concat [Wq;Wk;Wv]
    __bf16* wo_bf  = (__bf16*)(ws + 22 * MB);   // 2 MB
    __bf16* q_bf   = (__bf16*)(ws + 24 * MB);   // 16 MB
    __bf16* k_bf   = (__bf16*)(ws + 40 * MB);   // 16 MB
    __bf16* vt_bf  = (__bf16*)(ws + 56 * MB);   // 16 MB
    float*  msk2   = (float*)(ws + 72 * MB);    // 32 KB pre-scaled mask
    float*  bqkv   = (float*)(ws + 72 * MB + (64 << 10));  // 12 KB concat bias
    __bf16* ctx_bf = (__bf16*)(ws);             // aliases x_bf (x dead by then)
    float*  pre    = (float*)(ws + 24 * MB);    // 32 MB, aliases q/k (dead by then)

    const int nx = M_ * H_;
    const int nw = H_ * H_;
    cast_f32_bf16<<<nx / 2048, 256, 0, stream>>>(hs, x_bf, nx);
    cast_f32_bf16<<<nw / 2048, 256, 0, stream>>>(Wq, wqkv, nw);
    cast_f32_bf16<<<nw / 2048, 256, 0, stream>>>(Wk, wqkv + nw, nw);
    cast_f32_bf16<<<nw / 2048, 256, 0, stream>>>(Wv, wqkv + 2 * nw, nw);
    cast_f32_bf16<<<nw / 2048, 256, 0, stream>>>(Wo, wo_bf, nw);
    prescale_mask<<<B_ * S_ / 256, 256, 0, stream>>>(mask, msk2);
    hipMemcpyAsync(bqkv,        bq, H_ * sizeof(float), hipMemcpyDeviceToDevice, stream);
    hipMemcpyAsync(bqkv + H_,   bk, H_ * sizeof(float), hipMemcpyDeviceToDevice, stream);
    hipMemcpyAsync(bqkv + 2*H_, bv, H_ * sizeof(float), hipMemcpyDeviceToDevice, stream);

    // fused QKV projection: N = 3072 (seg 0=Q, 1=K, 2=V^T)
    gemm_bt<3><<<dim3(3 * H_ / 128, M_ / 128), 256, 0, stream>>>(
        x_bf, wqkv, bqkv, nullptr, nullptr, q_bf, k_bf, vt_bf);

    attn_fwd<<<dim3(S_ / 128 * NH_ * B_), 512, 0, stream>>>(q_bf, k_bf, vt_bf, msk2, ctx_bf);

    gemm_bt<1><<<dim3(H_ / 128, M_ / 128), 256, 0, stream>>>(
        ctx_bf, wo_bf, bo, hs, pre, nullptr, nullptr, nullptr);

    ln_kernel<<<M_, 256, 0, stream>>>(pre, gamma, beta, (float*)d_out);
}

// Round 12
// 215.150 us; speedup vs baseline: 1.1121x; 1.1121x over previous
//
#include <hip/hip_runtime.h>
#include <hip/hip_bf16.h>
#include <stdint.h>

#define B_ 4
#define S_ 2048
#define H_ 1024
#define NH_ 16
#define DH_ 64
#define M_ (B_*S_)   // 8192

typedef __bf16 bf16x8 __attribute__((ext_vector_type(8)));
typedef float f32x4 __attribute__((ext_vector_type(4)));

static_assert(sizeof(__bf16) == 2, "bf16 size");

__device__ __forceinline__ uint32_t pack_bf16(float lo, float hi)
{
    union { __bf16 h[2]; uint32_t u; } t;
    t.h[0] = (__bf16)lo; t.h[1] = (__bf16)hi;
    return t.u;
}

__device__ __forceinline__ float fast_exp2(float x)
{
#if __has_builtin(__builtin_amdgcn_exp2f)
    return __builtin_amdgcn_exp2f(x);
#else
    return exp2f(x);
#endif
}

// async global->LDS, 16B per lane. LDS dest = wave-uniform base + lane*16.
__device__ __forceinline__ void gll16(void* lds, const void* g)
{
    __builtin_amdgcn_global_load_lds(
        (const __attribute__((address_space(1))) unsigned int*)g,
        (__attribute__((address_space(3))) unsigned int*)lds,
        16, 0, 0);
}

// ----------------------------------------------------------------- prep ----
// ONE kernel: cast x (f32->bf16), cast Wq/Wk/Wv (concat) and Wo, prescale
// mask by log2e, concat biases. Segmented by blockIdx (block-uniform).
__device__ __forceinline__ void cast8(const float* __restrict__ s, __bf16* __restrict__ d, int i)
{
    float4 a = *(const float4*)(s + i);
    float4 b = *(const float4*)(s + i + 4);
    bf16x8 o;
    o[0] = (__bf16)a.x; o[1] = (__bf16)a.y; o[2] = (__bf16)a.z; o[3] = (__bf16)a.w;
    o[4] = (__bf16)b.x; o[5] = (__bf16)b.y; o[6] = (__bf16)b.z; o[7] = (__bf16)b.w;
    *(bf16x8*)(d + i) = o;
}

__global__ __launch_bounds__(256)
void prep_kernel(const float* __restrict__ hs,
                 const float* __restrict__ Wq, const float* __restrict__ Wk,
                 const float* __restrict__ Wv, const float* __restrict__ Wo,
                 const float* __restrict__ mask,
                 const float* __restrict__ bq, const float* __restrict__ bk,
                 const float* __restrict__ bv,
                 __bf16* __restrict__ x_bf, __bf16* __restrict__ wqkv,
                 __bf16* __restrict__ wo_bf, float* __restrict__ msk2,
                 float* __restrict__ bqkv)
{
    const int bid = blockIdx.x, tid = threadIdx.x;
    const int nw = H_ * H_;
    if (bid < 4096) {                                 // x: 8M elems
        cast8(hs, x_bf, bid * 2048 + tid * 8);
    } else if (bid < 4608) {                          // Wq
        cast8(Wq, wqkv, (bid - 4096) * 2048 + tid * 8);
    } else if (bid < 5120) {                          // Wk
        cast8(Wk, wqkv + nw, (bid - 4608) * 2048 + tid * 8);
    } else if (bid < 5632) {                          // Wv
        cast8(Wv, wqkv + 2 * nw, (bid - 5120) * 2048 + tid * 8);
    } else if (bid < 6144) {                          // Wo
        cast8(Wo, wo_bf, (bid - 5632) * 2048 + tid * 8);
    } else if (bid < 6148) {                          // mask * log2e (8192)
        const int i = (bid - 6144) * 2048 + tid * 8;
        float4 a = *(const float4*)(mask + i);
        float4 c = *(const float4*)(mask + i + 4);
        const float L = 1.44269504089f;
        float4 sa = {a.x * L, a.y * L, a.z * L, a.w * L};
        float4 sc = {c.x * L, c.y * L, c.z * L, c.w * L};
        *(float4*)(msk2 + i)     = sa;
        *(float4*)(msk2 + i + 4) = sc;
    } else {                                          // bias concat (3072)
        const int j = (bid - 6148) * 256 + tid;
        const float* src = (j < H_) ? bq : (j < 2 * H_) ? bk : bv;
        bqkv[j] = src[j & (H_ - 1)];
    }
}

// ---------------------------------------------------------------- GEMM ----
// C[M,N] = A[M,K] @ Bw[N,K]^T + bias. bf16 in, fp32 acc.
// EPI 1: fp32 out + resid (Wo proj). EPI 3: fused QKV -> q, k, V^T.
template<int EPI>
__global__ __launch_bounds__(256)
void gemm_bt(const __bf16* __restrict__ A, const __bf16* __restrict__ Bw,
             const float* __restrict__ bias, const float* __restrict__ resid,
             float* __restrict__ outf, __bf16* __restrict__ outq,
             __bf16* __restrict__ outk, __bf16* __restrict__ outvt)
{
    __shared__ __align__(16) char As[128 * 128];
    __shared__ __align__(16) char Bs[128 * 128];

    const int tid  = threadIdx.x;
    const int lane = tid & 63, wv = tid >> 6;
    const int wr = wv >> 1, wc = wv & 1;           // 2x2 wave grid, 64x64 each
    const int m0 = blockIdx.y * 128, n0 = blockIdx.x * 128;
    const int rl = lane & 15, rg = lane >> 4;
    const int r8 = lane >> 3, sl = lane & 7;       // staging: row-in-group, slot

    f32x4 acc[4][4] = {};

    for (int k0 = 0; k0 < H_; k0 += 64) {
#pragma unroll
        for (int p = 0; p < 4; ++p) {
            const int row = p * 32 + wv * 8 + r8;
            gll16(As + (size_t)(p * 32 + wv * 8) * 128,
                  A  + (size_t)(m0 + row) * H_ + k0 + 8 * (sl ^ (row & 7)));
            gll16(Bs + (size_t)(p * 32 + wv * 8) * 128,
                  Bw + (size_t)(n0 + row) * H_ + k0 + 8 * (sl ^ (row & 7)));
        }
        __syncthreads();
#pragma unroll
        for (int ks = 0; ks < 2; ++ks) {
            const int kb = ks * 64 + rg * 16;      // byte offset in LDS row
            bf16x8 af[4], bfr[4];
#pragma unroll
            for (int m = 0; m < 4; ++m) {
                const int row = wr * 64 + m * 16 + rl;
                af[m] = *(const bf16x8*)(As + row * 128 + (kb ^ ((rl & 7) << 4)));
            }
#pragma unroll
            for (int n = 0; n < 4; ++n) {
                const int row = wc * 64 + n * 16 + rl;
                bfr[n] = *(const bf16x8*)(Bs + row * 128 + (kb ^ ((rl & 7) << 4)));
            }
#pragma unroll
            for (int m = 0; m < 4; ++m)
#pragma unroll
                for (int n = 0; n < 4; ++n)
                    acc[m][n] = __builtin_amdgcn_mfma_f32_16x16x32_bf16(af[m], bfr[n], acc[m][n], 0, 0, 0);
        }
        __syncthreads();
    }

    // epilogue: C/D layout col = lane&15, row = (lane>>4)*4 + reg   [m89]
#pragma unroll
    for (int m = 0; m < 4; ++m) {
#pragma unroll
        for (int n = 0; n < 4; ++n) {
            const int col = n0 + wc * 64 + n * 16 + rl;
            const float bv = bias[col];
            const int row0 = m0 + wr * 64 + m * 16 + rg * 4;
            if (EPI == 1) {
#pragma unroll
                for (int r = 0; r < 4; ++r) {
                    const size_t idx = (size_t)(row0 + r) * H_ + col;
                    outf[idx] = acc[m][n][r] + bv + resid[idx];
                }
            } else {
                const int seg = n0 >> 10;          // block-uniform
                const int cs = col & 1023;
                if (seg < 2) {
                    __bf16* o = (seg == 0) ? outq : outk;
#pragma unroll
                    for (int r = 0; r < 4; ++r)
                        o[(size_t)(row0 + r) * H_ + cs] = (__bf16)(acc[m][n][r] + bv);
                } else {
                    const int bb = row0 >> 11, s0v = row0 & (S_ - 1);
                    const int hh = cs >> 6, dd = cs & (DH_ - 1);
                    __bf16* vtp = outvt + ((size_t)(bb * NH_ + hh) * DH_ + dd) * S_ + s0v;
                    *(uint32_t*)(vtp)     = pack_bf16(acc[m][n][0] + bv, acc[m][n][1] + bv);
                    *(uint32_t*)(vtp + 2) = pack_bf16(acc[m][n][2] + bv, acc[m][n][3] + bv);
                }
            }
        }
    }
}

// ------------------------------------------------------------ attention ----
// R10 structure (best measured: 96.5 us). Swapped QK^T + permuted-K LDS ->
// lane-local x32 B-fragments for PV & lsum (zero cross-lane). Fixed-m
// softmax. 32 q-rows/wave, 8-wave blocks (256 rows), KVBLK=128, 64 KB dbuf
// LDS, counted-vmcnt(4) double buffer, XCD-swizzled 512-block grid.
__global__ __launch_bounds__(512)
void attn_fwd(const __bf16* __restrict__ q, const __bf16* __restrict__ k,
              const __bf16* __restrict__ vt, const float* __restrict__ msk2,
              __bf16* __restrict__ ctx)
{
    __shared__ __align__(16) char KVs[2 * 32768];   // 64 KB exactly

    // XCD swizzle: phys%8 = XCD; 64 consecutive orig per XCD (8 heads).
    const int phys = blockIdx.x;
    const int orig = (phys & 7) * 64 + (phys >> 3);
    const int qt0 = (orig & 7) * 256;          // 8 q-tiles of 256 rows
    const int hg = orig >> 3;                  // global head 0..63
    const int h = hg & (NH_ - 1), b = hg >> 4;

    const int tid = threadIdx.x, lane = tid & 63, wv = tid >> 6;   // wv 0..7
    const int rl = lane & 15, rg = lane >> 4;
    const int swz = (rl & 7) << 4;
    const float SC = 0.125f * 1.44269504089f;      // 1/sqrt(64) * log2(e)
    const float* mbase2 = msk2 + (size_t)b * S_ + rg * 8;

    // Q as B-fragment (col = q = rl, k-elems dh = rg*8+j); wave owns 32 rows
    bf16x8 qf[2][2];
#pragma unroll
    for (int qm = 0; qm < 2; ++qm)
#pragma unroll
        for (int ks = 0; ks < 2; ++ks)
            qf[qm][ks] = *(const bf16x8*)(q + (size_t)(b * S_ + qt0 + wv * 32 + qm * 16 + rl) * H_
                                            + h * DH_ + ks * 32 + rg * 8);

    f32x4 cacc[2][4] = {};
    f32x4 lacc[2] = {};
    bf16x8 ones8;
#pragma unroll
    for (int i = 0; i < 8; ++i) ones8[i] = (__bf16)1.0f;

    // staging geometry (8 waves: 2 gll16 rounds each for K and V)
    const int kR = lane >> 3, kS = lane & 7;       // K: 8 rows/inst, 8 slots
    const int vR = lane >> 4, vS = lane & 15;      // V: 4 rows/inst, 16 slots
    const __bf16* kbase = k  + (size_t)b * S_ * H_ + h * DH_;
    const __bf16* vbase = vt + (size_t)(b * NH_ + h) * DH_ * S_;

    // K-row permutation: LDS row r holds physical key perm(r) of the tile
    auto permk = [](int r) {
        return ((r >> 5) << 5) + 8 * ((r >> 2) & 3) + 4 * ((r >> 4) & 1) + (r & 3);
    };

    auto stage = [&](int buf, int kt0) {
        char* Ks = KVs + buf * 32768;
        char* Vs = Ks + 16384;
#pragma unroll
        for (int p = 0; p < 2; ++p) {
            const int krow = p * 64 + wv * 8 + kR;
            gll16(Ks + (size_t)(p * 64 + wv * 8) * 128,
                  kbase + (size_t)(kt0 + permk(krow)) * H_ + 8 * (kS ^ (krow & 7)));
            const int vrow = p * 32 + wv * 4 + vR;
            gll16(Vs + (size_t)(p * 32 + wv * 4) * 256,
                  vbase + (size_t)vrow * S_ + kt0 + 8 * (vS ^ (vrow & 7)));
        }
    };

    stage(0, 0);                                    // prologue: tile 0 in flight

    const int NT = S_ / 128;
    for (int t = 0; t < NT; ++t) {
        const int cur = t & 1;
        const char* Ks = KVs + cur * 32768;
        const char* Vs = Ks + 16384;
        const int kt0 = t * 128;

        if (t + 1 < NT) {
            stage(cur ^ 1, kt0 + 128);              // issue next tile (4 loads)
            asm volatile("s_waitcnt vmcnt(4)" ::: "memory");  // tile t landed
        } else {
            asm volatile("s_waitcnt vmcnt(0)" ::: "memory");
        }
        __builtin_amdgcn_s_barrier();               // tile t visible to all
        __builtin_amdgcn_sched_barrier(0);

        // ---- per-32-key pipeline: QK(2 chunks) -> exp2/pack -> lsum+PV @x32
#pragma unroll
        for (int t4 = 0; t4 < 4; ++t4) {
            union { uint32_t u[4]; bf16x8 v; } pb0, pb1;
#pragma unroll
            for (int half = 0; half < 2; ++half) {
                const int c = 2 * t4 + half;
                bf16x8 kf0 = *(const bf16x8*)(Ks + (c * 16 + rl) * 128 + ((rg * 16) ^ swz));
                bf16x8 kf1 = *(const bf16x8*)(Ks + (c * 16 + rl) * 128 + ((64 + rg * 16) ^ swz));
                f32x4 s0 = {0, 0, 0, 0}, s1 = {0, 0, 0, 0};
                s0 = __builtin_amdgcn_mfma_f32_16x16x32_bf16(kf0, qf[0][0], s0, 0, 0, 0);
                s0 = __builtin_amdgcn_mfma_f32_16x16x32_bf16(kf1, qf[0][1], s0, 0, 0, 0);
                s1 = __builtin_amdgcn_mfma_f32_16x16x32_bf16(kf0, qf[1][0], s1, 0, 0, 0);
                s1 = __builtin_amdgcn_mfma_f32_16x16x32_bf16(kf1, qf[1][1], s1, 0, 0, 0);

                // physical keys 32*t4 + 8*rg + 4*half + {0..3}
                f32x4 m4 = *(const f32x4*)(mbase2 + kt0 + 32 * t4 + 4 * half);
                float p0 = fast_exp2(fmaf(s0[0], SC, m4[0]));
                float p1 = fast_exp2(fmaf(s0[1], SC, m4[1]));
                float p2 = fast_exp2(fmaf(s0[2], SC, m4[2]));
                float p3 = fast_exp2(fmaf(s0[3], SC, m4[3]));
                float u0 = fast_exp2(fmaf(s1[0], SC, m4[0]));
                float u1 = fast_exp2(fmaf(s1[1], SC, m4[1]));
                float u2 = fast_exp2(fmaf(s1[2], SC, m4[2]));
                float u3 = fast_exp2(fmaf(s1[3], SC, m4[3]));
                pb0.u[half * 2]     = pack_bf16(p0, p1);
                pb0.u[half * 2 + 1] = pack_bf16(p2, p3);
                pb1.u[half * 2]     = pack_bf16(u0, u1);
                pb1.u[half * 2 + 1] = pack_bf16(u2, u3);
            }
            lacc[0] = __builtin_amdgcn_mfma_f32_16x16x32_bf16(ones8, pb0.v, lacc[0], 0, 0, 0);
            lacc[1] = __builtin_amdgcn_mfma_f32_16x16x32_bf16(ones8, pb1.v, lacc[1], 0, 0, 0);
#pragma unroll
            for (int n = 0; n < 4; ++n) {
                bf16x8 af = *(const bf16x8*)(Vs + (n * 16 + rl) * 256 + ((t4 * 64 + rg * 16) ^ swz));
                cacc[0][n] = __builtin_amdgcn_mfma_f32_16x16x32_bf16(af, pb0.v, cacc[0][n], 0, 0, 0);
                cacc[1][n] = __builtin_amdgcn_mfma_f32_16x16x32_bf16(af, pb1.v, cacc[1][n], 0, 0, 0);
            }
        }

        // all reads of buf `cur` retired before next iter restages into it
        asm volatile("s_waitcnt lgkmcnt(0)" ::: "memory");
        __builtin_amdgcn_s_barrier();
    }

    // ---- normalize + write ctx [B,S,H] bf16 (O^T: lane has q=rl, d=rg*4+r)
#pragma unroll
    for (int qm = 0; qm < 2; ++qm) {
        const float inv = 1.f / lacc[qm][0];       // ones-MFMA: col-sum for q=rl
        const int row = qt0 + wv * 32 + qm * 16 + rl;
        __bf16* cb = ctx + (size_t)(b * S_ + row) * H_ + h * DH_;
#pragma unroll
        for (int n = 0; n < 4; ++n) {
            uint32_t u0 = pack_bf16(cacc[qm][n][0] * inv, cacc[qm][n][1] * inv);
            uint32_t u1 = pack_bf16(cacc[qm][n][2] * inv, cacc[qm][n][3] * inv);
            *(uint32_t*)(cb + n * 16 + rg * 4)     = u0;
            *(uint32_t*)(cb + n * 16 + rg * 4 + 2) = u1;
        }
    }
}

// ------------------------------------------------------------ layernorm ----
__global__ __launch_bounds__(256)
void ln_kernel(const float* __restrict__ x, const float* __restrict__ gamma,
               const float* __restrict__ beta, float* __restrict__ out)
{
    const int row = blockIdx.x;
    const int t = threadIdx.x;
    const float* xr = x + (size_t)row * H_;
    float4 v = *(const float4*)(xr + t * 4);
    float s  = v.x + v.y + v.z + v.w;
    float ss = v.x * v.x + v.y * v.y + v.z * v.z + v.w * v.w;
#pragma unroll
    for (int off = 1; off < 64; off <<= 1) {
        s  += __shfl_xor(s, off, 64);
        ss += __shfl_xor(ss, off, 64);
    }
    __shared__ float sb[8];
    const int wv = t >> 6, lane = t & 63;
    if (lane == 0) { sb[wv] = s; sb[4 + wv] = ss; }
    __syncthreads();
    s  = sb[0] + sb[1] + sb[2] + sb[3];
    ss = sb[4] + sb[5] + sb[6] + sb[7];
    const float mu = s * (1.f / H_);
    const float var = ss * (1.f / H_) - mu * mu;
    const float rstd = rsqrtf(var + 1e-12f);
    float4 g = *(const float4*)(gamma + t * 4);
    float4 bt = *(const float4*)(beta + t * 4);
    float4 o;
    o.x = (v.x - mu) * rstd * g.x + bt.x;
    o.y = (v.y - mu) * rstd * g.y + bt.y;
    o.z = (v.z - mu) * rstd * g.z + bt.z;
    o.w = (v.w - mu) * rstd * g.w + bt.w;
    *(float4*)(out + (size_t)row * H_ + t * 4) = o;
}

// -------------------------------------------------------------- launch ----
extern "C" void kernel_launch(void* const* d_in, const int* in_sizes, int n_in,
                              void* d_out, int out_size, void* d_ws, size_t ws_size,
                              hipStream_t stream)
{
    const float* hs    = (const float*)d_in[0];
    const float* mask  = (const float*)d_in[1];
    const float* Wq    = (const float*)d_in[2];
    const float* bq    = (const float*)d_in[3];
    const float* Wk    = (const float*)d_in[4];
    const float* bk    = (const float*)d_in[5];
    const float* Wv    = (const float*)d_in[6];
    const float* bv    = (const float*)d_in[7];
    const float* Wo    = (const float*)d_in[8];
    const float* bo    = (const float*)d_in[9];
    const float* gamma = (const float*)d_in[10];
    const float* beta  = (const float*)d_in[11];

    char* ws = (char*)d_ws;
    const size_t MB = 1ull << 20;
    __bf16* x_bf   = (__bf16*)(ws);             // 16 MB (dead after QKV GEMM)
    __bf16* wqkv   = (__bf16*)(ws + 16 * MB);   // 6 MB concat [Wq;Wk;Wv]
    __bf16* wo_bf  = (__bf16*)(ws + 22 * MB);   // 2 MB
    __bf16* q_bf   = (__bf16*)(ws + 24 * MB);   // 16 MB
    __bf16* k_bf   = (__bf16*)(ws + 40 * MB);   // 16 MB
    __bf16* vt_bf  = (__bf16*)(ws + 56 * MB);   // 16 MB
    float*  msk2   = (float*)(ws + 72 * MB);    // 32 KB pre-scaled mask
    float*  bqkv   = (float*)(ws + 72 * MB + (64 << 10));  // 12 KB concat bias
    __bf16* ctx_bf = (__bf16*)(ws);             // aliases x_bf (x dead by then)
    float*  pre    = (float*)(ws + 24 * MB);    // 32 MB, aliases q/k (dead by then)

    // single prep dispatch: all casts + mask prescale + bias concat
    prep_kernel<<<6160, 256, 0, stream>>>(hs, Wq, Wk, Wv, Wo, mask, bq, bk, bv,
                                          x_bf, wqkv, wo_bf, msk2, bqkv);

    // fused QKV projection: N = 3072 (seg 0=Q, 1=K, 2=V^T)
    gemm_bt<3><<<dim3(3 * H_ / 128, M_ / 128), 256, 0, stream>>>(
        x_bf, wqkv, bqkv, nullptr, nullptr, q_bf, k_bf, vt_bf);

    attn_fwd<<<dim3(S_ / 256 * NH_ * B_), 512, 0, stream>>>(q_bf, k_bf, vt_bf, msk2, ctx_bf);

    gemm_bt<1><<<dim3(H_ / 128, M_ / 128), 256, 0, stream>>>(
        ctx_bf, wo_bf, bo, hs, pre, nullptr, nullptr, nullptr);

    ln_kernel<<<M_, 256, 0, stream>>>(pre, gamma, beta, (float*)d_out);
}

// Round 13
// 203.072 us; speedup vs baseline: 1.1782x; 1.0595x over previous
//
#include <hip/hip_runtime.h>
#include <hip/hip_bf16.h>
#include <stdint.h>

#define B_ 4
#define S_ 2048
#define H_ 1024
#define NH_ 16
#define DH_ 64
#define M_ (B_*S_)   // 8192

typedef __bf16 bf16x8 __attribute__((ext_vector_type(8)));
typedef float f32x4 __attribute__((ext_vector_type(4)));

static_assert(sizeof(__bf16) == 2, "bf16 size");

__device__ __forceinline__ uint32_t pack_bf16(float lo, float hi)
{
    union { __bf16 h[2]; uint32_t u; } t;
    t.h[0] = (__bf16)lo; t.h[1] = (__bf16)hi;
    return t.u;
}

__device__ __forceinline__ float fast_exp2(float x)
{
#if __has_builtin(__builtin_amdgcn_exp2f)
    return __builtin_amdgcn_exp2f(x);
#else
    return exp2f(x);
#endif
}

// async global->LDS, 16B per lane. LDS dest = wave-uniform base + lane*16.
__device__ __forceinline__ void gll16(void* lds, const void* g)
{
    __builtin_amdgcn_global_load_lds(
        (const __attribute__((address_space(1))) unsigned int*)g,
        (__attribute__((address_space(3))) unsigned int*)lds,
        16, 0, 0);
}

// ----------------------------------------------------------------- prep ----
__device__ __forceinline__ void cast8(const float* __restrict__ s, __bf16* __restrict__ d, int i)
{
    float4 a = *(const float4*)(s + i);
    float4 b = *(const float4*)(s + i + 4);
    bf16x8 o;
    o[0] = (__bf16)a.x; o[1] = (__bf16)a.y; o[2] = (__bf16)a.z; o[3] = (__bf16)a.w;
    o[4] = (__bf16)b.x; o[5] = (__bf16)b.y; o[6] = (__bf16)b.z; o[7] = (__bf16)b.w;
    *(bf16x8*)(d + i) = o;
}

__global__ __launch_bounds__(256)
void prep_kernel(const float* __restrict__ hs,
                 const float* __restrict__ Wq, const float* __restrict__ Wk,
                 const float* __restrict__ Wv, const float* __restrict__ Wo,
                 const float* __restrict__ mask,
                 const float* __restrict__ bq, const float* __restrict__ bk,
                 const float* __restrict__ bv,
                 __bf16* __restrict__ x_bf, __bf16* __restrict__ wqkv,
                 __bf16* __restrict__ wo_bf, float* __restrict__ msk2,
                 float* __restrict__ bqkv)
{
    const int bid = blockIdx.x, tid = threadIdx.x;
    const int nw = H_ * H_;
    if (bid < 4096) {
        cast8(hs, x_bf, bid * 2048 + tid * 8);
    } else if (bid < 4608) {
        cast8(Wq, wqkv, (bid - 4096) * 2048 + tid * 8);
    } else if (bid < 5120) {
        cast8(Wk, wqkv + nw, (bid - 4608) * 2048 + tid * 8);
    } else if (bid < 5632) {
        cast8(Wv, wqkv + 2 * nw, (bid - 5120) * 2048 + tid * 8);
    } else if (bid < 6144) {
        cast8(Wo, wo_bf, (bid - 5632) * 2048 + tid * 8);
    } else if (bid < 6148) {
        const int i = (bid - 6144) * 2048 + tid * 8;
        float4 a = *(const float4*)(mask + i);
        float4 c = *(const float4*)(mask + i + 4);
        const float L = 1.44269504089f;
        float4 sa = {a.x * L, a.y * L, a.z * L, a.w * L};
        float4 sc = {c.x * L, c.y * L, c.z * L, c.w * L};
        *(float4*)(msk2 + i)     = sa;
        *(float4*)(msk2 + i + 4) = sc;
    } else {
        const int j = (bid - 6148) * 256 + tid;
        const float* src = (j < H_) ? bq : (j < 2 * H_) ? bk : bv;
        bqkv[j] = src[j & (H_ - 1)];
    }
}

// ---------------------------------------------------------------- GEMM ----
// C[M,N] = A[M,K] @ Bw[N,K]^T + bias. bf16 in, fp32 acc.
// EPI 1: bf16 out + resid (Wo proj; LN reads bf16).
// EPI 3: fused QKV -> q bf16, k bf16, V^T via LDS-transposed coalesced write.
template<int EPI>
__global__ __launch_bounds__(256)
void gemm_bt(const __bf16* __restrict__ A, const __bf16* __restrict__ Bw,
             const float* __restrict__ bias, const float* __restrict__ resid,
             __bf16* __restrict__ outq, __bf16* __restrict__ outk,
             __bf16* __restrict__ outvt)
{
    __shared__ __align__(16) char LB[2 * 16384];
    char* As = LB;
    char* Bs = LB + 16384;

    const int tid  = threadIdx.x;
    const int lane = tid & 63, wv = tid >> 6;
    const int wr = wv >> 1, wc = wv & 1;           // 2x2 wave grid, 64x64 each
    const int m0 = blockIdx.y * 128, n0 = blockIdx.x * 128;
    const int rl = lane & 15, rg = lane >> 4;
    const int r8 = lane >> 3, sl = lane & 7;       // staging: row-in-group, slot

    f32x4 acc[4][4] = {};

    for (int k0 = 0; k0 < H_; k0 += 64) {
#pragma unroll
        for (int p = 0; p < 4; ++p) {
            const int row = p * 32 + wv * 8 + r8;
            gll16(As + (size_t)(p * 32 + wv * 8) * 128,
                  A  + (size_t)(m0 + row) * H_ + k0 + 8 * (sl ^ (row & 7)));
            gll16(Bs + (size_t)(p * 32 + wv * 8) * 128,
                  Bw + (size_t)(n0 + row) * H_ + k0 + 8 * (sl ^ (row & 7)));
        }
        __syncthreads();
#pragma unroll
        for (int ks = 0; ks < 2; ++ks) {
            const int kb = ks * 64 + rg * 16;      // byte offset in LDS row
            bf16x8 af[4], bfr[4];
#pragma unroll
            for (int m = 0; m < 4; ++m) {
                const int row = wr * 64 + m * 16 + rl;
                af[m] = *(const bf16x8*)(As + row * 128 + (kb ^ ((rl & 7) << 4)));
            }
#pragma unroll
            for (int n = 0; n < 4; ++n) {
                const int row = wc * 64 + n * 16 + rl;
                bfr[n] = *(const bf16x8*)(Bs + row * 128 + (kb ^ ((rl & 7) << 4)));
            }
#pragma unroll
            for (int m = 0; m < 4; ++m)
#pragma unroll
                for (int n = 0; n < 4; ++n)
                    acc[m][n] = __builtin_amdgcn_mfma_f32_16x16x32_bf16(af[m], bfr[n], acc[m][n], 0, 0, 0);
        }
        __syncthreads();
    }

    // epilogue: C/D layout col = lane&15, row = (lane>>4)*4 + reg   [m89]
    if (EPI == 3 && (n0 >> 10) == 2) {
        // ---- V^T: transpose the 128x128 tile in LDS (XOR-swizzled), then
        //      coalesced 16B stores (row = d, contiguous in s).
#pragma unroll
        for (int m = 0; m < 4; ++m)
#pragma unroll
            for (int n = 0; n < 4; ++n) {
                const int lcol = wc * 64 + n * 16 + rl;      // local d
                const int ls0  = wr * 64 + m * 16 + rg * 4;  // local s
                const float bv = bias[n0 + lcol];
                uint32_t w0 = pack_bf16(acc[m][n][0] + bv, acc[m][n][1] + bv);
                uint32_t w1 = pack_bf16(acc[m][n][2] + bv, acc[m][n][3] + bv);
                const int xorv = (lcol & 15) << 4;
                *(uint32_t*)(LB + lcol * 256 + ((ls0 * 2) ^ xorv))           = w0;
                *(uint32_t*)(LB + lcol * 256 + (((ls0 + 2) * 2) ^ xorv))     = w1;
            }
        __syncthreads();
        const int bb = m0 >> 11, s0g = m0 & (S_ - 1);
#pragma unroll
        for (int pass = 0; pass < 4; ++pass) {
            const int dd = pass * 32 + wv * 8 + (lane >> 3);
            const int ch = (lane & 7) * 16;                  // byte chunk in row
            const int cs = (n0 & 1023) + dd;
            const int hh = cs >> 6, dv = cs & 63;
            __bf16* dst = outvt + ((size_t)(bb * NH_ + hh) * DH_ + dv) * S_ + s0g;
#pragma unroll
            for (int c = 0; c < 2; ++c) {
                bf16x8 vvv = *(const bf16x8*)(LB + dd * 256 + ((ch + c * 128) ^ ((dd & 15) << 4)));
                *(bf16x8*)(dst + (ch >> 1) + c * 64) = vvv;
            }
        }
    } else {
#pragma unroll
        for (int m = 0; m < 4; ++m)
#pragma unroll
            for (int n = 0; n < 4; ++n) {
                const int col = n0 + wc * 64 + n * 16 + rl;
                const float bv = bias[col];
                const int row0 = m0 + wr * 64 + m * 16 + rg * 4;
                if (EPI == 1) {
#pragma unroll
                    for (int r = 0; r < 4; ++r) {
                        const size_t idx = (size_t)(row0 + r) * H_ + col;
                        outq[idx] = (__bf16)(acc[m][n][r] + bv + resid[idx]);
                    }
                } else {
                    const int seg = n0 >> 10;          // 0=Q, 1=K (block-uniform)
                    const int cs = col & 1023;
                    __bf16* o = (seg == 0) ? outq : outk;
#pragma unroll
                    for (int r = 0; r < 4; ++r)
                        o[(size_t)(row0 + r) * H_ + cs] = (__bf16)(acc[m][n][r] + bv);
                }
            }
    }
}

// ------------------------------------------------------------ attention ----
// Swapped QK^T + permuted-K LDS -> lane-local x32 B-fragments for PV & lsum
// (zero cross-lane). Fixed-m softmax. 32 q-rows/wave, 8-wave blocks, KVBLK
// =128, 64 KB dbuf. SINGLE barrier per tile: waitcnt(vmcnt0+lgkm0) proves
// prior-tile reads done and current tile landed; stage issued AFTER the
// barrier into the buffer everyone just finished with. setprio(1) around
// the PV MFMA cluster (T5). Staging via 4 running pointers.
__global__ __launch_bounds__(512)
void attn_fwd(const __bf16* __restrict__ q, const __bf16* __restrict__ k,
              const __bf16* __restrict__ vt, const float* __restrict__ msk2,
              __bf16* __restrict__ ctx)
{
    __shared__ __align__(16) char KVs[2 * 32768];   // 64 KB exactly

    // XCD swizzle: phys%8 = XCD; 64 consecutive orig per XCD (8 heads).
    const int phys = blockIdx.x;
    const int orig = (phys & 7) * 64 + (phys >> 3);
    const int qt0 = (orig & 7) * 256;          // 8 q-tiles of 256 rows
    const int hg = orig >> 3;                  // global head 0..63
    const int h = hg & (NH_ - 1), b = hg >> 4;

    const int tid = threadIdx.x, lane = tid & 63, wv = tid >> 6;   // wv 0..7
    const int rl = lane & 15, rg = lane >> 4;
    const int swz = (rl & 7) << 4;
    const float SC = 0.125f * 1.44269504089f;      // 1/sqrt(64) * log2(e)
    const float* mptr = msk2 + (size_t)b * S_ + rg * 8;

    // Q as B-fragment (col = q = rl, k-elems dh = rg*8+j); wave owns 32 rows
    bf16x8 qf[2][2];
#pragma unroll
    for (int qm = 0; qm < 2; ++qm)
#pragma unroll
        for (int ks = 0; ks < 2; ++ks)
            qf[qm][ks] = *(const bf16x8*)(q + (size_t)(b * S_ + qt0 + wv * 32 + qm * 16 + rl) * H_
                                            + h * DH_ + ks * 32 + rg * 8);

    f32x4 cacc[2][4] = {};
    f32x4 lacc[2] = {};
    bf16x8 ones8;
#pragma unroll
    for (int i = 0; i < 8; ++i) ones8[i] = (__bf16)1.0f;

    // staging geometry (8 waves: 2 gll16 rounds each for K and V)
    const int kR = lane >> 3, kS = lane & 7;       // K: 8 rows/inst, 8 slots
    const int vR = lane >> 4, vS = lane & 15;      // V: 4 rows/inst, 16 slots
    const __bf16* kbase = k  + (size_t)b * S_ * H_ + h * DH_;
    const __bf16* vbase = vt + (size_t)(b * NH_ + h) * DH_ * S_;

    // K-row permutation: LDS row r holds physical key perm(r) of the tile
    auto permk = [](int r) {
        return ((r >> 5) << 5) + 8 * ((r >> 2) & 3) + 4 * ((r >> 4) & 1) + (r & 3);
    };

    // running per-thread source pointers (advance per tile)
    const int krow0 = wv * 8 + kR, krow1 = 64 + krow0;
    const int vrow0 = wv * 4 + vR, vrow1 = 32 + vrow0;
    const __bf16* kp0 = kbase + (size_t)permk(krow0) * H_ + 8 * (kS ^ (krow0 & 7));
    const __bf16* kp1 = kbase + (size_t)permk(krow1) * H_ + 8 * (kS ^ (krow1 & 7));
    const __bf16* vp0 = vbase + (size_t)vrow0 * S_ + 8 * (vS ^ (vrow0 & 7));
    const __bf16* vp1 = vbase + (size_t)vrow1 * S_ + 8 * (vS ^ (vrow1 & 7));
    const int kd0 = (wv * 8) * 128, kd1 = (64 + wv * 8) * 128;
    const int vd0 = 16384 + (wv * 4) * 256, vd1 = 16384 + (32 + wv * 4) * 256;

    // prologue: stage tile 0 into buf 0
    gll16(KVs + kd0, kp0); gll16(KVs + kd1, kp1);
    gll16(KVs + vd0, vp0); gll16(KVs + vd1, vp1);
    kp0 += 128 * H_; kp1 += 128 * H_; vp0 += 128; vp1 += 128;

    const int NT = S_ / 128;
    int cur = 0;
    for (int t = 0; t < NT; ++t) {
        // tile t landed (issued a full tile ago) + my prior-tile LDS reads done
        asm volatile("s_waitcnt vmcnt(0) lgkmcnt(0)" ::: "memory");
        __builtin_amdgcn_s_barrier();               // all waves: safe to reuse buf
        __builtin_amdgcn_sched_barrier(0);

        if (t + 1 < NT) {                           // stage tile t+1 into other buf
            char* nb = KVs + (cur ^ 1) * 32768;
            gll16(nb + kd0, kp0); gll16(nb + kd1, kp1);
            gll16(nb + vd0, vp0); gll16(nb + vd1, vp1);
            kp0 += 128 * H_; kp1 += 128 * H_; vp0 += 128; vp1 += 128;
        }

        const char* Ks = KVs + cur * 32768;
        const char* Vs = Ks + 16384;
        const float* mrow = mptr + t * 128;

        // ---- per-32-key pipeline: QK(2 chunks) -> exp2/pack -> lsum+PV @x32
#pragma unroll
        for (int t4 = 0; t4 < 4; ++t4) {
            union { uint32_t u[4]; bf16x8 v; } pb0, pb1;
#pragma unroll
            for (int half = 0; half < 2; ++half) {
                const int c = 2 * t4 + half;
                bf16x8 kf0 = *(const bf16x8*)(Ks + (c * 16 + rl) * 128 + ((rg * 16) ^ swz));
                bf16x8 kf1 = *(const bf16x8*)(Ks + (c * 16 + rl) * 128 + ((64 + rg * 16) ^ swz));
                f32x4 s0 = {0, 0, 0, 0}, s1 = {0, 0, 0, 0};
                s0 = __builtin_amdgcn_mfma_f32_16x16x32_bf16(kf0, qf[0][0], s0, 0, 0, 0);
                s0 = __builtin_amdgcn_mfma_f32_16x16x32_bf16(kf1, qf[0][1], s0, 0, 0, 0);
                s1 = __builtin_amdgcn_mfma_f32_16x16x32_bf16(kf0, qf[1][0], s1, 0, 0, 0);
                s1 = __builtin_amdgcn_mfma_f32_16x16x32_bf16(kf1, qf[1][1], s1, 0, 0, 0);

                // physical keys 32*t4 + 8*rg + 4*half + {0..3}
                f32x4 m4 = *(const f32x4*)(mrow + 32 * t4 + 4 * half);
                float p0 = fast_exp2(fmaf(s0[0], SC, m4[0]));
                float p1 = fast_exp2(fmaf(s0[1], SC, m4[1]));
                float p2 = fast_exp2(fmaf(s0[2], SC, m4[2]));
                float p3 = fast_exp2(fmaf(s0[3], SC, m4[3]));
                float u0 = fast_exp2(fmaf(s1[0], SC, m4[0]));
                float u1 = fast_exp2(fmaf(s1[1], SC, m4[1]));
                float u2 = fast_exp2(fmaf(s1[2], SC, m4[2]));
                float u3 = fast_exp2(fmaf(s1[3], SC, m4[3]));
                pb0.u[half * 2]     = pack_bf16(p0, p1);
                pb0.u[half * 2 + 1] = pack_bf16(p2, p3);
                pb1.u[half * 2]     = pack_bf16(u0, u1);
                pb1.u[half * 2 + 1] = pack_bf16(u2, u3);
            }
            __builtin_amdgcn_s_setprio(1);
            lacc[0] = __builtin_amdgcn_mfma_f32_16x16x32_bf16(ones8, pb0.v, lacc[0], 0, 0, 0);
            lacc[1] = __builtin_amdgcn_mfma_f32_16x16x32_bf16(ones8, pb1.v, lacc[1], 0, 0, 0);
#pragma unroll
            for (int n = 0; n < 4; ++n) {
                bf16x8 af = *(const bf16x8*)(Vs + (n * 16 + rl) * 256 + ((t4 * 64 + rg * 16) ^ swz));
                cacc[0][n] = __builtin_amdgcn_mfma_f32_16x16x32_bf16(af, pb0.v, cacc[0][n], 0, 0, 0);
                cacc[1][n] = __builtin_amdgcn_mfma_f32_16x16x32_bf16(af, pb1.v, cacc[1][n], 0, 0, 0);
            }
            __builtin_amdgcn_s_setprio(0);
        }
        cur ^= 1;
    }

    // ---- normalize + write ctx [B,S,H] bf16 (O^T: lane has q=rl, d=rg*4+r)
#pragma unroll
    for (int qm = 0; qm < 2; ++qm) {
        const float inv = 1.f / lacc[qm][0];       // ones-MFMA: col-sum for q=rl
        const int row = qt0 + wv * 32 + qm * 16 + rl;
        __bf16* cb = ctx + (size_t)(b * S_ + row) * H_ + h * DH_;
#pragma unroll
        for (int n = 0; n < 4; ++n) {
            uint32_t u0 = pack_bf16(cacc[qm][n][0] * inv, cacc[qm][n][1] * inv);
            uint32_t u1 = pack_bf16(cacc[qm][n][2] * inv, cacc[qm][n][3] * inv);
            *(uint32_t*)(cb + n * 16 + rg * 4)     = u0;
            *(uint32_t*)(cb + n * 16 + rg * 4 + 2) = u1;
        }
    }
}

// ------------------------------------------------------------ layernorm ----
// bf16 input (pre), fp32 output.
__global__ __launch_bounds__(256)
void ln_kernel(const __bf16* __restrict__ x, const float* __restrict__ gamma,
               const float* __restrict__ beta, float* __restrict__ out)
{
    const int row = blockIdx.x;
    const int t = threadIdx.x;
    const unsigned short* xr = (const unsigned short*)(x + (size_t)row * H_);
    ushort4 raw = *(const ushort4*)(xr + t * 4);
    union { uint32_t u; float f; } c0, c1, c2, c3;
    c0.u = (uint32_t)raw.x << 16; c1.u = (uint32_t)raw.y << 16;
    c2.u = (uint32_t)raw.z << 16; c3.u = (uint32_t)raw.w << 16;
    float v0 = c0.f, v1 = c1.f, v2 = c2.f, v3 = c3.f;
    float s  = v0 + v1 + v2 + v3;
    float ss = v0 * v0 + v1 * v1 + v2 * v2 + v3 * v3;
#pragma unroll
    for (int off = 1; off < 64; off <<= 1) {
        s  += __shfl_xor(s, off, 64);
        ss += __shfl_xor(ss, off, 64);
    }
    __shared__ float sb[8];
    const int wv = t >> 6, lane = t & 63;
    if (lane == 0) { sb[wv] = s; sb[4 + wv] = ss; }
    __syncthreads();
    s  = sb[0] + sb[1] + sb[2] + sb[3];
    ss = sb[4] + sb[5] + sb[6] + sb[7];
    const float mu = s * (1.f / H_);
    const float var = ss * (1.f / H_) - mu * mu;
    const float rstd = rsqrtf(var + 1e-12f);
    float4 g = *(const float4*)(gamma + t * 4);
    float4 bt = *(const float4*)(beta + t * 4);
    float4 o;
    o.x = (v0 - mu) * rstd * g.x + bt.x;
    o.y = (v1 - mu) * rstd * g.y + bt.y;
    o.z = (v2 - mu) * rstd * g.z + bt.z;
    o.w = (v3 - mu) * rstd * g.w + bt.w;
    *(float4*)(out + (size_t)row * H_ + t * 4) = o;
}

// -------------------------------------------------------------- launch ----
extern "C" void kernel_launch(void* const* d_in, const int* in_sizes, int n_in,
                              void* d_out, int out_size, void* d_ws, size_t ws_size,
                              hipStream_t stream)
{
    const float* hs    = (const float*)d_in[0];
    const float* mask  = (const float*)d_in[1];
    const float* Wq    = (const float*)d_in[2];
    const float* bq    = (const float*)d_in[3];
    const float* Wk    = (const float*)d_in[4];
    const float* bk    = (const float*)d_in[5];
    const float* Wv    = (const float*)d_in[6];
    const float* bv    = (const float*)d_in[7];
    const float* Wo    = (const float*)d_in[8];
    const float* bo    = (const float*)d_in[9];
    const float* gamma = (const float*)d_in[10];
    const float* beta  = (const float*)d_in[11];

    char* ws = (char*)d_ws;
    const size_t MB = 1ull << 20;
    __bf16* x_bf   = (__bf16*)(ws);             // 16 MB (dead after QKV GEMM)
    __bf16* wqkv   = (__bf16*)(ws + 16 * MB);   // 6 MB concat [Wq;Wk;Wv]
    __bf16* wo_bf  = (__bf16*)(ws + 22 * MB);   // 2 MB
    __bf16* q_bf   = (__bf16*)(ws + 24 * MB);   // 16 MB (later pre_bf)
    __bf16* k_bf   = (__bf16*)(ws + 40 * MB);   // 16 MB
    __bf16* vt_bf  = (__bf16*)(ws + 56 * MB);   // 16 MB
    float*  msk2   = (float*)(ws + 72 * MB);    // 32 KB pre-scaled mask
    float*  bqkv   = (float*)(ws + 72 * MB + (64 << 10));  // 12 KB concat bias
    __bf16* ctx_bf = (__bf16*)(ws);             // aliases x_bf (x dead by then)
    __bf16* pre_bf = (__bf16*)(ws + 24 * MB);   // 16 MB, aliases q (dead by then)

    // single prep dispatch: all casts + mask prescale + bias concat
    prep_kernel<<<6160, 256, 0, stream>>>(hs, Wq, Wk, Wv, Wo, mask, bq, bk, bv,
                                          x_bf, wqkv, wo_bf, msk2, bqkv);

    // fused QKV projection: N = 3072 (seg 0=Q, 1=K, 2=V^T via LDS transpose)
    gemm_bt<3><<<dim3(3 * H_ / 128, M_ / 128), 256, 0, stream>>>(
        x_bf, wqkv, bqkv, nullptr, q_bf, k_bf, vt_bf);

    attn_fwd<<<dim3(S_ / 256 * NH_ * B_), 512, 0, stream>>>(q_bf, k_bf, vt_bf, msk2, ctx_bf);

    // Wo proj + bias + residual -> bf16 pre
    gemm_bt<1><<<dim3(H_ / 128, M_ / 128), 256, 0, stream>>>(
        ctx_bf, wo_bf, bo, hs, pre_bf, nullptr, nullptr);

    ln_kernel<<<M_, 256, 0, stream>>>(pre_bf, gamma, beta, (float*)d_out);
}